// Round 4
// baseline (694.159 us; speedup 1.0000x reference)
//
#include <hip/hip_runtime.h>

#define BH 16
#define L 2048
#define D 64
#define QB 16
#define KB 64
#define NKT (L / KB)
#define SCALE 0.125f
#define MASK_FILL -65504.0f

typedef __bf16 bf16x8 __attribute__((ext_vector_type(8)));
typedef float f32x4 __attribute__((ext_vector_type(4)));

__device__ __forceinline__ unsigned f2bf(float f) {
    union { float f; unsigned u; } x; x.f = f;
    return (x.u + 0x7FFFu + ((x.u >> 16) & 1u)) >> 16;   // RNE
}
__device__ __forceinline__ float bf2f(unsigned short h) {
    union { unsigned u; float f; } x; x.u = ((unsigned)h) << 16;
    return x.f;
}

// ========================= fused pre-pass kernel ==========================
// blocks [0,2048): mask -> TRANSPOSED bitmask wsM2[row][col] (u32, bit kt =
//                  mask[row][kt*64+col]) -- one word per (row,col), so the
//                  main kernel loads its 4 mask words ONCE.
// blocks [2048,3072): K fp32 -> bf16 chunk-swizzled
// blocks [3072,3584): V fp32 -> bf16 transposed+tiled
extern "C" __global__ __launch_bounds__(256)
void prep(const float* __restrict__ k, const float* __restrict__ v,
          const int* __restrict__ mask,
          uint4* __restrict__ wsK, uint4* __restrict__ wsVt,
          unsigned* __restrict__ wsM2)
{
    __shared__ float sT[64 * 68];                 // used by preV branch only
    const int b = blockIdx.x;
    const int t = threadIdx.x;

    if (b < 2048) {
        // ---- preM (transposed): 16 rows per block, no ballot/LDS needed ----
        size_t row0 = (size_t)b * 16;
        int lane = t & 63, w4 = t >> 6;
        const int* src = mask + row0 * L;
        unsigned* dst = wsM2 + row0 * 64;
        for (int rr = 0; rr < 4; ++rr) {
            int r = w4 * 4 + rr;
            unsigned word = 0;
            #pragma unroll
            for (int kt = 0; kt < 32; ++kt) {
                int val = __builtin_nontemporal_load(src + (size_t)r * L + kt * 64 + lane);
                word |= (val != 0 ? 1u : 0u) << kt;
            }
            dst[(size_t)r * 64 + lane] = word;    // coalesced 256B per row
        }
    } else if (b < 3072) {
        // ---- preK ----
        int idx = (b - 2048) * 256 + t;           // 0..262143 chunks
        int c   = idx & 7;
        int key = (idx >> 3) & (L - 1);
        int bh  = idx >> 14;
        const float4* src = (const float4*)(k + ((size_t)(bh * L + key) * D + c * 8));
        float4 a = src[0], bb = src[1];
        uint4 o;
        o.x = f2bf(a.x)  | (f2bf(a.y)  << 16);
        o.y = f2bf(a.z)  | (f2bf(a.w)  << 16);
        o.z = f2bf(bb.x) | (f2bf(bb.y) << 16);
        o.w = f2bf(bb.z) | (f2bf(bb.w) << 16);
        wsK[(size_t)(bh * L + key) * 8 + (c ^ (key & 7))] = o;
    } else {
        // ---- preV ----
        int bb = b - 3072;                        // 16*32 tiles
        int bh = bb >> 5, kt = bb & 31;
        const float4* src = (const float4*)(v + ((size_t)bh * L + kt * 64) * D);
        #pragma unroll
        for (int i = 0; i < 4; ++i) {
            int i4 = i * 256 + t;                 // 1024 float4s = 64x64 tile
            int key = i4 >> 4, c4 = i4 & 15;
            float4 val = src[i4];
            *(float4*)&sT[key * 68 + c4 * 4] = val;
        }
        __syncthreads();
        int d = t >> 2, cg = t & 3;
        #pragma unroll
        for (int j = 0; j < 2; ++j) {
            int c = cg + j * 4;                   // key-chunk 0..7
            unsigned pk[4];
            #pragma unroll
            for (int e = 0; e < 4; ++e) {
                float x0 = sT[(c * 8 + e * 2    ) * 68 + d];
                float x1 = sT[(c * 8 + e * 2 + 1) * 68 + d];
                pk[e] = f2bf(x0) | (f2bf(x1) << 16);
            }
            wsVt[((size_t)(bh * 32 + kt) * 64 + d) * 8 + (c ^ (d & 7))] =
                make_uint4(pk[0], pk[1], pk[2], pk[3]);
        }
    }
}

// ============================== main kernel ================================
// Round-4 structure (round-2 dataflow + two fixes):
//  * QB=16, grid 2048, slim state -> __launch_bounds__(256,8): 8 blocks/CU
//    = 32 waves/CU (round 2 had 16) for latency hiding
//  * transposed bitmask: each lane loads its 4 mask words ONCE before pass 1
//    (round 2 paid 8 L2 u64 loads per kt with ~40cyc load-to-use distance)
//  * SCALE folded into Q bf16 conversion (exact: 0.125 = 2^-3)
//  * regular stores (round-3 NT stores caused RMW write amplification)
//  * pass 1: zero barriers, 2-deep K register prefetch
//  * pass 2: 1 lgkm-only barrier per kt (no vmcnt drain), K/V prefetched

extern "C" __global__ __launch_bounds__(256, 8)
void sdpa_main(const float* __restrict__ q, const uint4* __restrict__ gKall,
               const uint4* __restrict__ gVall, const unsigned* __restrict__ wsM2,
               float* __restrict__ out, float* __restrict__ attn)
{
    __shared__ unsigned short sP[2][QB * 72];    // padded stride for A-frag reads
    __shared__ float sPart[4][16];

    const int tid = threadIdx.x, lane = tid & 63, w = tid >> 6;
    const int wn = w;                            // key-16 slice per wave
    const int quad = lane >> 4, l15 = lane & 15;
    const int p = blockIdx.x, bh = p & 15, qb = p >> 4, q0 = qb * QB;

    const uint4* gK = gKall + (size_t)bh * L * 8;
    const uint4* gV = gVall + (size_t)bh * L * 8;

    // ---- Q fragments straight from global, pre-scaled by 0.125 (exact) ----
    const float* Qp = q + (size_t)(bh * L + q0 + l15) * D + quad * 8;
    float4 qv0 = *(const float4*)(Qp);
    float4 qv1 = *(const float4*)(Qp + 4);
    float4 qv2 = *(const float4*)(Qp + 32);
    float4 qv3 = *(const float4*)(Qp + 36);
    union { bf16x8 v; unsigned short s[8]; } qa0u, qa1u;
    qa0u.s[0] = f2bf(qv0.x * SCALE); qa0u.s[1] = f2bf(qv0.y * SCALE);
    qa0u.s[2] = f2bf(qv0.z * SCALE); qa0u.s[3] = f2bf(qv0.w * SCALE);
    qa0u.s[4] = f2bf(qv1.x * SCALE); qa0u.s[5] = f2bf(qv1.y * SCALE);
    qa0u.s[6] = f2bf(qv1.z * SCALE); qa0u.s[7] = f2bf(qv1.w * SCALE);
    qa1u.s[0] = f2bf(qv2.x * SCALE); qa1u.s[1] = f2bf(qv2.y * SCALE);
    qa1u.s[2] = f2bf(qv2.z * SCALE); qa1u.s[3] = f2bf(qv2.w * SCALE);
    qa1u.s[4] = f2bf(qv3.x * SCALE); qa1u.s[5] = f2bf(qv3.y * SCALE);
    qa1u.s[6] = f2bf(qv3.z * SCALE); qa1u.s[7] = f2bf(qv3.w * SCALE);
    const bf16x8 qa0 = qa0u.v, qa1 = qa1u.v;

    // per-lane fragment offsets (lane-constant across kt; swizzle folds in)
    const int key = wn * 16 + l15;               // this wave's key / output-d
    const int s7 = l15 & 7;
    const int oA = key * 8 + ((quad    ) ^ s7);
    const int oB = key * 8 + ((quad + 4) ^ s7);

    auto loadK = [&](int kt, bf16x8& a, bf16x8& b) {
        const uint4* base = gK + (size_t)kt * 512;
        a = *(const bf16x8*)(base + oA);
        b = *(const bf16x8*)(base + oB);
    };
    auto loadV = [&](int kt, bf16x8& a, bf16x8& b) {
        const uint4* base = gV + (size_t)kt * 512;
        a = *(const bf16x8*)(base + oA);
        b = *(const bf16x8*)(base + oB);
    };

    // ---- mask words: ONE load per q-row, bit kt = mask[row][kt*64+key] ----
    const unsigned* Mp = wsM2 + ((size_t)(bh * L) + q0 + quad * 4) * 64 + key;
    unsigned mb[4];
    #pragma unroll
    for (int r = 0; r < 4; ++r) mb[r] = Mp[r * 64];

    // ===================== PASS 1: row sums of exp =====================
    float lsum[4] = {0.f, 0.f, 0.f, 0.f};

    bf16x8 kA0, kA1, kB0, kB1;
    loadK(0, kA0, kA1);
    loadK(1, kB0, kB1);

    for (int kt = 0; kt < NKT; kt += 2) {
        // ---- even sub-iteration: consumes kA ----
        {
            f32x4 acc = (f32x4){0.f, 0.f, 0.f, 0.f};
            acc = __builtin_amdgcn_mfma_f32_16x16x32_bf16(qa0, kA0, acc, 0, 0, 0);
            acc = __builtin_amdgcn_mfma_f32_16x16x32_bf16(qa1, kA1, acc, 0, 0, 0);
            if (kt + 2 < NKT) loadK(kt + 2, kA0, kA1);   // 2-deep prefetch
            #pragma unroll
            for (int r = 0; r < 4; ++r) {
                float e = __expf(acc[r]);
                lsum[r] += ((mb[r] >> kt) & 1u) ? 0.f : e;
            }
        }
        // ---- odd sub-iteration: consumes kB ----
        {
            f32x4 acc = (f32x4){0.f, 0.f, 0.f, 0.f};
            acc = __builtin_amdgcn_mfma_f32_16x16x32_bf16(qa0, kB0, acc, 0, 0, 0);
            acc = __builtin_amdgcn_mfma_f32_16x16x32_bf16(qa1, kB1, acc, 0, 0, 0);
            if (kt + 3 < NKT) loadK(kt + 3, kB0, kB1);   // 2-deep prefetch
            #pragma unroll
            for (int r = 0; r < 4; ++r) {
                float e = __expf(acc[r]);
                lsum[r] += ((mb[r] >> (kt + 1)) & 1u) ? 0.f : e;
            }
        }
    }

    #pragma unroll
    for (int off = 1; off < 16; off <<= 1)
        #pragma unroll
        for (int r = 0; r < 4; ++r) lsum[r] += __shfl_xor(lsum[r], off, 64);
    if (l15 == 0) {
        #pragma unroll
        for (int r = 0; r < 4; ++r) sPart[w][quad * 4 + r] = lsum[r];
    }
    __syncthreads();
    float rinv[4];
    #pragma unroll
    for (int r = 0; r < 4; ++r)
        rinv[r] = 1.0f / (sPart[0][quad * 4 + r] + sPart[1][quad * 4 + r] +
                          sPart[2][quad * 4 + r] + sPart[3][quad * 4 + r]);

    // ===================== PASS 2: attn + O = P@V =====================
    f32x4 oacc = (f32x4){0.f, 0.f, 0.f, 0.f};
    float* Ab = attn + ((size_t)bh * L + q0) * L;

    bf16x8 k0c, k1c, v0c, v1c;
    loadK(0, k0c, k1c);
    loadV(0, v0c, v1c);
    for (int kt = 0; kt < NKT; ++kt) {
        f32x4 acc = (f32x4){0.f, 0.f, 0.f, 0.f};
        acc = __builtin_amdgcn_mfma_f32_16x16x32_bf16(qa0, k0c, acc, 0, 0, 0);
        acc = __builtin_amdgcn_mfma_f32_16x16x32_bf16(qa1, k1c, acc, 0, 0, 0);

        unsigned short* sPb = sP[kt & 1];
        #pragma unroll
        for (int r = 0; r < 4; ++r) {
            float e = __expf(acc[r]);
            float pr = (((mb[r] >> kt) & 1u) ? 0.f : e) * rinv[r];
            const int row = quad * 4 + r;
            Ab[(size_t)row * L + kt * 64 + key] = pr;          // fp32 attn
            sPb[row * 72 + key] = (unsigned short)f2bf(pr);    // bf16 for PV
        }
        // lgkm-only barrier: LDS writes visible; attn stores + K/V prefetch
        // stay in flight (no vmcnt drain).
        asm volatile("s_waitcnt lgkmcnt(0)\n\ts_barrier" ::: "memory");

        if (kt + 1 < NKT) loadK(kt + 1, k0c, k1c);             // prefetch K

        const bf16x8 pa0 = *(const bf16x8*)&sPb[l15 * 72 + quad * 8];
        const bf16x8 pa1 = *(const bf16x8*)&sPb[l15 * 72 + quad * 8 + 32];
        oacc = __builtin_amdgcn_mfma_f32_16x16x32_bf16(pa0, v0c, oacc, 0, 0, 0);
        oacc = __builtin_amdgcn_mfma_f32_16x16x32_bf16(pa1, v1c, oacc, 0, 0, 0);
        if (kt + 1 < NKT) loadV(kt + 1, v0c, v1c);             // prefetch V
    }

    float* Ob = out + ((size_t)bh * L + q0) * D;
    #pragma unroll
    for (int r = 0; r < 4; ++r)
        Ob[(size_t)(quad * 4 + r) * D + key] = oacc[r];
}

// ===================== fallback (round-1 kernel, known good) ==============

extern "C" __global__ __launch_bounds__(256, 2)
void sdpa_kernel(const float* __restrict__ q, const float* __restrict__ k,
                 const float* __restrict__ v, const int* __restrict__ mask,
                 float* __restrict__ out, float* __restrict__ attn)
{
    __shared__ unsigned short fQ[64 * 72];
    __shared__ unsigned short fK[64 * 72];
    __shared__ unsigned short fVt[64 * 72];
    __shared__ unsigned short fP[64 * 72];
    __shared__ unsigned long long fM[64 * 33];

    const int tid  = threadIdx.x;
    const int lane = tid & 63;
    const int w    = tid >> 6;
    const int quad = lane >> 4;
    const int l15  = lane & 15;

    const int p  = blockIdx.x;
    const int bh = p & (BH - 1);
    const int qb = p >> 4;
    const int q0 = qb * 64;

    const size_t base = (size_t)bh * L * D;
    const float* Qb = q + base + (size_t)q0 * D;
    const float* Kb = k + base;
    const float* Vb = v + base;
    const int*   Mb = mask + (size_t)bh * L * L + (size_t)q0 * L;
    float*       Ab = attn + (size_t)bh * L * L + (size_t)q0 * L;
    float*       Ob = out  + base + (size_t)q0 * D;

    {
        const float2* Qs = (const float2*)Qb;
        for (int i = 0; i < 8; ++i) {
            int idx = i * 256 + tid;
            int row = idx >> 5, d2 = idx & 31;
            float2 val = Qs[idx];
            unsigned pk = f2bf(val.x) | (f2bf(val.y) << 16);
            *(unsigned*)&fQ[row * 72 + d2 * 2] = pk;
        }
    }
    for (int rr = 0; rr < 16; ++rr) {
        int row = w * 16 + rr;
        const int4* Ms = (const int4*)(Mb + (size_t)row * L);
        for (int it = 0; it < 8; ++it) {
            int4 mv = Ms[it * 64 + lane];
            unsigned long long b0 = __ballot(mv.x != 0);
            unsigned long long b1 = __ballot(mv.y != 0);
            unsigned long long b2 = __ballot(mv.z != 0);
            unsigned long long b3 = __ballot(mv.w != 0);
            if (lane == 0) {
                unsigned long long* dst = &fM[row * 33 + it * 4];
                dst[0] = b0; dst[1] = b1; dst[2] = b2; dst[3] = b3;
            }
        }
    }
    __syncthreads();

    const int qrow = w * 16 + l15;
    bf16x8 qa0 = *(const bf16x8*)&fQ[qrow * 72 + quad * 8];
    bf16x8 qa1 = *(const bf16x8*)&fQ[qrow * 72 + quad * 8 + 32];

    float lsum[4] = {0.f, 0.f, 0.f, 0.f};
    for (int kt = 0; kt < 32; ++kt) {
        const int k0 = kt * 64;
        __syncthreads();
        {
            const float2* Ks = (const float2*)(Kb + (size_t)k0 * D);
            for (int i = 0; i < 8; ++i) {
                int idx = i * 256 + tid;
                int row = idx >> 5, d2 = idx & 31;
                float2 val = Ks[idx];
                unsigned pk = f2bf(val.x) | (f2bf(val.y) << 16);
                *(unsigned*)&fK[row * 72 + d2 * 2] = pk;
            }
        }
        __syncthreads();
        f32x4 acc[4];
        for (int nt = 0; nt < 4; ++nt) {
            bf16x8 b0 = *(const bf16x8*)&fK[(nt * 16 + l15) * 72 + quad * 8];
            bf16x8 b1 = *(const bf16x8*)&fK[(nt * 16 + l15) * 72 + quad * 8 + 32];
            f32x4 c = {0.f, 0.f, 0.f, 0.f};
            c = __builtin_amdgcn_mfma_f32_16x16x32_bf16(qa0, b0, c, 0, 0, 0);
            c = __builtin_amdgcn_mfma_f32_16x16x32_bf16(qa1, b1, c, 0, 0, 0);
            acc[nt] = c;
        }
        const int widx = (k0 >> 8) * 4 + (lane & 3);
        const int bsh0 = (k0 >> 2) + (l15 >> 2);
        for (int r = 0; r < 4; ++r) {
            int row = w * 16 + quad * 4 + r;
            unsigned long long mwv = fM[row * 33 + widx];
            float s = 0.f;
            for (int nt = 0; nt < 4; ++nt) {
                float val = acc[nt][r] * SCALE;
                int bit = (int)((mwv >> ((bsh0 + nt * 4) & 63)) & 1ull);
                val = bit ? MASK_FILL : val;
                s += __expf(val);
            }
            lsum[r] += s;
        }
    }
    for (int off = 1; off < 16; off <<= 1)
        for (int r = 0; r < 4; ++r) lsum[r] += __shfl_xor(lsum[r], off, 64);
    float rinv[4];
    for (int r = 0; r < 4; ++r) rinv[r] = 1.0f / lsum[r];

    f32x4 oacc[4];
    for (int nt = 0; nt < 4; ++nt) oacc[nt] = (f32x4){0.f, 0.f, 0.f, 0.f};

    for (int kt = 0; kt < 32; ++kt) {
        const int k0 = kt * 64;
        __syncthreads();
        {
            const float2* Ks = (const float2*)(Kb + (size_t)k0 * D);
            for (int i = 0; i < 8; ++i) {
                int idx = i * 256 + tid;
                int row = idx >> 5, d2 = idx & 31;
                float2 val = Ks[idx];
                unsigned pk = f2bf(val.x) | (f2bf(val.y) << 16);
                *(unsigned*)&fK[row * 72 + d2 * 2] = pk;
            }
        }
        {
            unsigned pk[8];
            for (int jj = 0; jj < 16; ++jj) {
                float val = Vb[(size_t)(k0 + w * 16 + jj) * D + lane];
                unsigned bv = f2bf(val);
                if (jj & 1) pk[jj >> 1] |= bv << 16;
                else        pk[jj >> 1]  = bv;
            }
            uint4* dst = (uint4*)&fVt[lane * 72 + w * 16];
            dst[0] = make_uint4(pk[0], pk[1], pk[2], pk[3]);
            dst[1] = make_uint4(pk[4], pk[5], pk[6], pk[7]);
        }
        __syncthreads();
        f32x4 acc[4];
        for (int nt = 0; nt < 4; ++nt) {
            bf16x8 b0 = *(const bf16x8*)&fK[(nt * 16 + l15) * 72 + quad * 8];
            bf16x8 b1 = *(const bf16x8*)&fK[(nt * 16 + l15) * 72 + quad * 8 + 32];
            f32x4 c = {0.f, 0.f, 0.f, 0.f};
            c = __builtin_amdgcn_mfma_f32_16x16x32_bf16(qa0, b0, c, 0, 0, 0);
            c = __builtin_amdgcn_mfma_f32_16x16x32_bf16(qa1, b1, c, 0, 0, 0);
            acc[nt] = c;
        }
        const int widx = (k0 >> 8) * 4 + (lane & 3);
        const int bsh0 = (k0 >> 2) + (l15 >> 2);
        for (int r = 0; r < 4; ++r) {
            int row = w * 16 + quad * 4 + r;
            unsigned long long mwv = fM[row * 33 + widx];
            for (int nt = 0; nt < 4; ++nt) {
                float val = acc[nt][r] * SCALE;
                int bit = (int)((mwv >> ((bsh0 + nt * 4) & 63)) & 1ull);
                val = bit ? MASK_FILL : val;
                float pr = __expf(val) * rinv[r];
                fP[row * 72 + nt * 16 + l15] = (unsigned short)f2bf(pr);
            }
        }
        for (int it = 0; it < 4; ++it) {
            int row = w * 16 + it * 4 + quad;
            unsigned long long pv = *(const unsigned long long*)&fP[row * 72 + l15 * 4];
            float4 o;
            o.x = bf2f((unsigned short)(pv         & 0xFFFF));
            o.y = bf2f((unsigned short)((pv >> 16) & 0xFFFF));
            o.z = bf2f((unsigned short)((pv >> 32) & 0xFFFF));
            o.w = bf2f((unsigned short)((pv >> 48) & 0xFFFF));
            *(float4*)&Ab[(size_t)row * L + k0 + l15 * 4] = o;
        }
        {
            bf16x8 pa0 = *(const bf16x8*)&fP[qrow * 72 + quad * 8];
            bf16x8 pa1 = *(const bf16x8*)&fP[qrow * 72 + quad * 8 + 32];
            for (int nt = 0; nt < 4; ++nt) {
                bf16x8 vb0 = *(const bf16x8*)&fVt[(nt * 16 + l15) * 72 + quad * 8];
                bf16x8 vb1 = *(const bf16x8*)&fVt[(nt * 16 + l15) * 72 + quad * 8 + 32];
                oacc[nt] = __builtin_amdgcn_mfma_f32_16x16x32_bf16(pa0, vb0, oacc[nt], 0, 0, 0);
                oacc[nt] = __builtin_amdgcn_mfma_f32_16x16x32_bf16(pa1, vb1, oacc[nt], 0, 0, 0);
            }
        }
    }
    for (int nt = 0; nt < 4; ++nt)
        for (int r = 0; r < 4; ++r)
            Ob[(size_t)(w * 16 + quad * 4 + r) * D + nt * 16 + l15] = oacc[nt][r];
}

// ============================== launch ====================================

extern "C" void kernel_launch(void* const* d_in, const int* in_sizes, int n_in,
                              void* d_out, int out_size, void* d_ws, size_t ws_size,
                              hipStream_t stream)
{
    const float* q    = (const float*)d_in[0];
    const float* k    = (const float*)d_in[1];
    const float* v    = (const float*)d_in[2];
    const int*   mask = (const int*)d_in[3];
    float* out  = (float*)d_out;
    float* attn = out + (size_t)BH * L * D;

    const size_t WS_K  = 0;
    const size_t WS_VT = (size_t)BH * L * D * 2;            // 4 MB
    const size_t WS_M  = WS_VT + (size_t)BH * L * D * 2;    // 8 MB
    const size_t NEED  = WS_M + (size_t)BH * L * 64 * 4;    // 16 MB

    if (ws_size >= NEED) {
        uint4* wsK  = (uint4*)((char*)d_ws + WS_K);
        uint4* wsVt = (uint4*)((char*)d_ws + WS_VT);
        unsigned* wsM2 = (unsigned*)((char*)d_ws + WS_M);
        hipLaunchKernelGGL(prep, dim3(3584), dim3(256), 0, stream,
                           k, v, mask, wsK, wsVt, wsM2);
        hipLaunchKernelGGL(sdpa_main, dim3(BH * (L / QB)), dim3(256), 0, stream,
                           q, (const uint4*)wsK, (const uint4*)wsVt, wsM2, out, attn);
    } else {
        hipLaunchKernelGGL(sdpa_kernel, dim3(BH * (L / 64)), dim3(256), 0, stream,
                           q, k, v, mask, out, attn);
    }
}

// Round 5
// 506.655 us; speedup vs baseline: 1.3701x; 1.3701x over previous
//
#include <hip/hip_runtime.h>

#define BH 16
#define L 2048
#define D 64
#define QB 64                 // rows per block (16 per wave x 4 waves)
#define KB 64
#define NKT (L / KB)
#define SCALE 0.125f
#define MASK_FILL -65504.0f

typedef __bf16 bf16x8 __attribute__((ext_vector_type(8)));
typedef float f32x4 __attribute__((ext_vector_type(4)));

__device__ __forceinline__ unsigned f2bf(float f) {
    union { float f; unsigned u; } x; x.f = f;
    return (x.u + 0x7FFFu + ((x.u >> 16) & 1u)) >> 16;   // RNE
}
__device__ __forceinline__ float bf2f(unsigned short h) {
    union { unsigned u; float f; } x; x.u = ((unsigned)h) << 16;
    return x.f;
}

// ========================= fused pre-pass kernel ==========================
// blocks [0,2048): mask -> TRANSPOSED bitmask wsM2[row][col] (u32, bit kt =
//                  mask[row][kt*64+col])
// blocks [2048,3072): K fp32 -> bf16 chunk-swizzled
// blocks [3072,3584): V fp32 -> bf16 transposed+tiled
extern "C" __global__ __launch_bounds__(256)
void prep(const float* __restrict__ k, const float* __restrict__ v,
          const int* __restrict__ mask,
          uint4* __restrict__ wsK, uint4* __restrict__ wsVt,
          unsigned* __restrict__ wsM2)
{
    __shared__ float sT[64 * 68];                 // used by preV branch only
    const int b = blockIdx.x;
    const int t = threadIdx.x;

    if (b < 2048) {
        // ---- preM (transposed): 16 rows per block ----
        size_t row0 = (size_t)b * 16;
        int lane = t & 63, w4 = t >> 6;
        const int* src = mask + row0 * L;
        unsigned* dst = wsM2 + row0 * 64;
        for (int rr = 0; rr < 4; ++rr) {
            int r = w4 * 4 + rr;
            unsigned word = 0;
            #pragma unroll
            for (int kt = 0; kt < 32; ++kt) {
                int val = __builtin_nontemporal_load(src + (size_t)r * L + kt * 64 + lane);
                word |= (val != 0 ? 1u : 0u) << kt;
            }
            dst[(size_t)r * 64 + lane] = word;    // coalesced 256B per row
        }
    } else if (b < 3072) {
        // ---- preK ----
        int idx = (b - 2048) * 256 + t;           // 0..262143 chunks
        int c   = idx & 7;
        int key = (idx >> 3) & (L - 1);
        int bh  = idx >> 14;
        const float4* src = (const float4*)(k + ((size_t)(bh * L + key) * D + c * 8));
        float4 a = src[0], bb = src[1];
        uint4 o;
        o.x = f2bf(a.x)  | (f2bf(a.y)  << 16);
        o.y = f2bf(a.z)  | (f2bf(a.w)  << 16);
        o.z = f2bf(bb.x) | (f2bf(bb.y) << 16);
        o.w = f2bf(bb.z) | (f2bf(bb.w) << 16);
        wsK[(size_t)(bh * L + key) * 8 + (c ^ (key & 7))] = o;
    } else {
        // ---- preV ----
        int bb = b - 3072;                        // 16*32 tiles
        int bh = bb >> 5, kt = bb & 31;
        const float4* src = (const float4*)(v + ((size_t)bh * L + kt * 64) * D);
        #pragma unroll
        for (int i = 0; i < 4; ++i) {
            int i4 = i * 256 + t;                 // 1024 float4s = 64x64 tile
            int key = i4 >> 4, c4 = i4 & 15;
            float4 val = src[i4];
            *(float4*)&sT[key * 68 + c4 * 4] = val;
        }
        __syncthreads();
        int d = t >> 2, cg = t & 3;
        #pragma unroll
        for (int j = 0; j < 2; ++j) {
            int c = cg + j * 4;                   // key-chunk 0..7
            unsigned pk[4];
            #pragma unroll
            for (int e = 0; e < 4; ++e) {
                float x0 = sT[(c * 8 + e * 2    ) * 68 + d];
                float x1 = sT[(c * 8 + e * 2 + 1) * 68 + d];
                pk[e] = f2bf(x0) | (f2bf(x1) << 16);
            }
            wsVt[((size_t)(bh * 32 + kt) * 64 + d) * 8 + (c ^ (d & 7))] =
                make_uint4(pk[0], pk[1], pk[2], pk[3]);
        }
    }
}

// ============================== main kernel ================================
// Round-5: WAVE-AUTONOMOUS flash structure.
//  * each wave owns 16 q-rows and computes the FULL 64-key tile (8 QK MFMAs)
//    -> P never crosses waves -> per-wave LDS transpose scratch, NO barriers
//    anywhere in the kernel (same-wave DS ops are in-order; compiler lgkmcnt)
//  * each wave writes complete 256B attn row segments -> no half-line write
//    amplification (round-4 bug)
//  * transposed bitmask loaded once (16 words/lane); SCALE folded into Q
//  * K double-buffered in regs (alternating named sets); V issued early
//  * grid 512, 256 thr, ~190 VGPR -> 2 blocks/CU, high per-wave ILP

struct KF { bf16x8 f[8]; };   // one 64-key x 64-k tile fragment set (static idx)

extern "C" __global__ __launch_bounds__(256, 2)
void sdpa_main(const float* __restrict__ q, const uint4* __restrict__ gKall,
               const uint4* __restrict__ gVall, const unsigned* __restrict__ wsM2,
               float* __restrict__ out, float* __restrict__ attn)
{
    __shared__ unsigned short sP[4][2][16 * 72];  // [wave][buf][row][col(pad)]

    const int tid = threadIdx.x, lane = tid & 63, w = tid >> 6;
    const int quad = lane >> 4, l15 = lane & 15;
    const int p = blockIdx.x, bh = p & 15, qb = p >> 4;
    const int row0 = qb * QB + w * 16;            // wave's first q-row

    const uint4* gK = gKall + (size_t)bh * L * 8;
    const uint4* gV = gVall + (size_t)bh * L * 8;

    // ---- Q A-fragments (row = l15), pre-scaled by 0.125 (exact) ----
    const float* Qp = q + (size_t)(bh * L + row0 + l15) * D + quad * 8;
    float4 qv0 = *(const float4*)(Qp);
    float4 qv1 = *(const float4*)(Qp + 4);
    float4 qv2 = *(const float4*)(Qp + 32);
    float4 qv3 = *(const float4*)(Qp + 36);
    union { bf16x8 v; unsigned short s[8]; } qa0u, qa1u;
    qa0u.s[0] = f2bf(qv0.x * SCALE); qa0u.s[1] = f2bf(qv0.y * SCALE);
    qa0u.s[2] = f2bf(qv0.z * SCALE); qa0u.s[3] = f2bf(qv0.w * SCALE);
    qa0u.s[4] = f2bf(qv1.x * SCALE); qa0u.s[5] = f2bf(qv1.y * SCALE);
    qa0u.s[6] = f2bf(qv1.z * SCALE); qa0u.s[7] = f2bf(qv1.w * SCALE);
    qa1u.s[0] = f2bf(qv2.x * SCALE); qa1u.s[1] = f2bf(qv2.y * SCALE);
    qa1u.s[2] = f2bf(qv2.z * SCALE); qa1u.s[3] = f2bf(qv2.w * SCALE);
    qa1u.s[4] = f2bf(qv3.x * SCALE); qa1u.s[5] = f2bf(qv3.y * SCALE);
    qa1u.s[6] = f2bf(qv3.z * SCALE); qa1u.s[7] = f2bf(qv3.w * SCALE);
    const bf16x8 qa0 = qa0u.v, qa1 = qa1u.v;

    // ---- per-lane fragment offsets within one 64-key tile (swizzle folded) ----
    const int s7 = l15 & 7;
    int off[8];
    #pragma unroll
    for (int nt = 0; nt < 4; ++nt) {
        off[nt * 2    ] = (nt * 16 + l15) * 8 + ((quad    ) ^ s7);
        off[nt * 2 + 1] = (nt * 16 + l15) * 8 + ((quad + 4) ^ s7);
    }

    auto loadT = [&](const uint4* base, KF& d) {
        #pragma unroll
        for (int i = 0; i < 8; ++i) d.f[i] = *(const bf16x8*)(base + off[i]);
    };

    // ---- mask words, ONE load each: bit kt = mask[row][kt*64+col] ----
    const unsigned* Mp = wsM2 + ((size_t)(bh * L) + row0 + quad * 4) * 64 + l15;
    unsigned mb[16];
    #pragma unroll
    for (int r = 0; r < 4; ++r)
        #pragma unroll
        for (int nt = 0; nt < 4; ++nt)
            mb[r * 4 + nt] = Mp[r * 64 + nt * 16];

    // ===================== PASS 1: row sums of exp =====================
    float lsum[4] = {0.f, 0.f, 0.f, 0.f};

    KF ka, kb;
    loadT(gK, ka);
    loadT(gK + 512, kb);

    for (int kt = 0; kt < NKT; kt += 2) {
        // ---- even sub-iteration: consumes ka ----
        {
            f32x4 acc[4];
            #pragma unroll
            for (int nt = 0; nt < 4; ++nt) {
                acc[nt] = (f32x4){0.f, 0.f, 0.f, 0.f};
                acc[nt] = __builtin_amdgcn_mfma_f32_16x16x32_bf16(qa0, ka.f[nt*2  ], acc[nt], 0, 0, 0);
                acc[nt] = __builtin_amdgcn_mfma_f32_16x16x32_bf16(qa1, ka.f[nt*2+1], acc[nt], 0, 0, 0);
            }
            if (kt + 2 < NKT) loadT(gK + (size_t)(kt + 2) * 512, ka);
            #pragma unroll
            for (int nt = 0; nt < 4; ++nt)
                #pragma unroll
                for (int r = 0; r < 4; ++r) {
                    float e = __expf(acc[nt][r]);
                    lsum[r] += ((mb[r * 4 + nt] >> kt) & 1u) ? 0.f : e;
                }
        }
        // ---- odd sub-iteration: consumes kb ----
        {
            f32x4 acc[4];
            #pragma unroll
            for (int nt = 0; nt < 4; ++nt) {
                acc[nt] = (f32x4){0.f, 0.f, 0.f, 0.f};
                acc[nt] = __builtin_amdgcn_mfma_f32_16x16x32_bf16(qa0, kb.f[nt*2  ], acc[nt], 0, 0, 0);
                acc[nt] = __builtin_amdgcn_mfma_f32_16x16x32_bf16(qa1, kb.f[nt*2+1], acc[nt], 0, 0, 0);
            }
            if (kt + 3 < NKT) loadT(gK + (size_t)(kt + 3) * 512, kb);
            #pragma unroll
            for (int nt = 0; nt < 4; ++nt)
                #pragma unroll
                for (int r = 0; r < 4; ++r) {
                    float e = __expf(acc[nt][r]);
                    lsum[r] += ((mb[r * 4 + nt] >> (kt + 1)) & 1u) ? 0.f : e;
                }
        }
    }

    // wave-local reduce across the 16 l15 lanes of each quad group
    #pragma unroll
    for (int o = 1; o < 16; o <<= 1)
        #pragma unroll
        for (int r = 0; r < 4; ++r) lsum[r] += __shfl_xor(lsum[r], o, 64);
    float rinv[4];
    #pragma unroll
    for (int r = 0; r < 4; ++r) rinv[r] = 1.0f / lsum[r];

    // ===================== PASS 2: attn + O = P@V (barrier-free) =====================
    f32x4 oacc[4];
    #pragma unroll
    for (int d = 0; d < 4; ++d) oacc[d] = (f32x4){0.f, 0.f, 0.f, 0.f};
    float* Ab = attn + ((size_t)bh * L + row0) * L;

    unsigned short* sw0 = &sP[w][0][0];
    unsigned short* sw1 = &sP[w][1][0];

    KF kc, kn, vc;
    loadT(gK, kc);

    for (int kt = 0; kt < NKT; kt += 2) {
        // ================= even sub-iteration: K=kc, LDS buf 0 =================
        {
            loadT(gV + (size_t)kt * 512, vc);              // V for this sub-iter
            f32x4 acc[4];
            #pragma unroll
            for (int nt = 0; nt < 4; ++nt) {
                acc[nt] = (f32x4){0.f, 0.f, 0.f, 0.f};
                acc[nt] = __builtin_amdgcn_mfma_f32_16x16x32_bf16(qa0, kc.f[nt*2  ], acc[nt], 0, 0, 0);
                acc[nt] = __builtin_amdgcn_mfma_f32_16x16x32_bf16(qa1, kc.f[nt*2+1], acc[nt], 0, 0, 0);
            }
            loadT(gK + (size_t)(kt + 1) * 512, kn);        // prefetch next K
            #pragma unroll
            for (int nt = 0; nt < 4; ++nt)
                #pragma unroll
                for (int r = 0; r < 4; ++r) {
                    float e = __expf(acc[nt][r]);
                    float pr = (((mb[r * 4 + nt] >> kt) & 1u) ? 0.f : e) * rinv[r];
                    const int row = quad * 4 + r;
                    Ab[(size_t)row * L + kt * 64 + nt * 16 + l15] = pr;
                    sw0[row * 72 + nt * 16 + l15] = (unsigned short)f2bf(pr);
                }
            // same-wave LDS transpose read (compiler inserts lgkmcnt; no barrier)
            const bf16x8 pa0 = *(const bf16x8*)&sw0[l15 * 72 + quad * 8];
            const bf16x8 pa1 = *(const bf16x8*)&sw0[l15 * 72 + quad * 8 + 32];
            #pragma unroll
            for (int d = 0; d < 4; ++d) {
                oacc[d] = __builtin_amdgcn_mfma_f32_16x16x32_bf16(pa0, vc.f[d*2  ], oacc[d], 0, 0, 0);
                oacc[d] = __builtin_amdgcn_mfma_f32_16x16x32_bf16(pa1, vc.f[d*2+1], oacc[d], 0, 0, 0);
            }
        }
        // ================= odd sub-iteration: K=kn, LDS buf 1 =================
        {
            loadT(gV + (size_t)(kt + 1) * 512, vc);
            f32x4 acc[4];
            #pragma unroll
            for (int nt = 0; nt < 4; ++nt) {
                acc[nt] = (f32x4){0.f, 0.f, 0.f, 0.f};
                acc[nt] = __builtin_amdgcn_mfma_f32_16x16x32_bf16(qa0, kn.f[nt*2  ], acc[nt], 0, 0, 0);
                acc[nt] = __builtin_amdgcn_mfma_f32_16x16x32_bf16(qa1, kn.f[nt*2+1], acc[nt], 0, 0, 0);
            }
            if (kt + 2 < NKT) loadT(gK + (size_t)(kt + 2) * 512, kc);   // prefetch
            #pragma unroll
            for (int nt = 0; nt < 4; ++nt)
                #pragma unroll
                for (int r = 0; r < 4; ++r) {
                    float e = __expf(acc[nt][r]);
                    float pr = (((mb[r * 4 + nt] >> (kt + 1)) & 1u) ? 0.f : e) * rinv[r];
                    const int row = quad * 4 + r;
                    Ab[(size_t)row * L + (kt + 1) * 64 + nt * 16 + l15] = pr;
                    sw1[row * 72 + nt * 16 + l15] = (unsigned short)f2bf(pr);
                }
            const bf16x8 pa0 = *(const bf16x8*)&sw1[l15 * 72 + quad * 8];
            const bf16x8 pa1 = *(const bf16x8*)&sw1[l15 * 72 + quad * 8 + 32];
            #pragma unroll
            for (int d = 0; d < 4; ++d) {
                oacc[d] = __builtin_amdgcn_mfma_f32_16x16x32_bf16(pa0, vc.f[d*2  ], oacc[d], 0, 0, 0);
                oacc[d] = __builtin_amdgcn_mfma_f32_16x16x32_bf16(pa1, vc.f[d*2+1], oacc[d], 0, 0, 0);
            }
        }
    }

    float* Ob = out + ((size_t)bh * L + row0) * D;
    #pragma unroll
    for (int d = 0; d < 4; ++d)
        #pragma unroll
        for (int r = 0; r < 4; ++r)
            Ob[(size_t)(quad * 4 + r) * D + d * 16 + l15] = oacc[d][r];
}

// ===================== fallback (round-1 kernel, known good) ==============

extern "C" __global__ __launch_bounds__(256, 2)
void sdpa_kernel(const float* __restrict__ q, const float* __restrict__ k,
                 const float* __restrict__ v, const int* __restrict__ mask,
                 float* __restrict__ out, float* __restrict__ attn)
{
    __shared__ unsigned short fQ[64 * 72];
    __shared__ unsigned short fK[64 * 72];
    __shared__ unsigned short fVt[64 * 72];
    __shared__ unsigned short fP[64 * 72];
    __shared__ unsigned long long fM[64 * 33];

    const int tid  = threadIdx.x;
    const int lane = tid & 63;
    const int w    = tid >> 6;
    const int quad = lane >> 4;
    const int l15  = lane & 15;

    const int p  = blockIdx.x;
    const int bh = p & (BH - 1);
    const int qb = p >> 4;
    const int q0 = qb * 64;

    const size_t base = (size_t)bh * L * D;
    const float* Qb = q + base + (size_t)q0 * D;
    const float* Kb = k + base;
    const float* Vb = v + base;
    const int*   Mb = mask + (size_t)bh * L * L + (size_t)q0 * L;
    float*       Ab = attn + (size_t)bh * L * L + (size_t)q0 * L;
    float*       Ob = out  + base + (size_t)q0 * D;

    {
        const float2* Qs = (const float2*)Qb;
        for (int i = 0; i < 8; ++i) {
            int idx = i * 256 + tid;
            int row = idx >> 5, d2 = idx & 31;
            float2 val = Qs[idx];
            unsigned pk = f2bf(val.x) | (f2bf(val.y) << 16);
            *(unsigned*)&fQ[row * 72 + d2 * 2] = pk;
        }
    }
    for (int rr = 0; rr < 16; ++rr) {
        int row = w * 16 + rr;
        const int4* Ms = (const int4*)(Mb + (size_t)row * L);
        for (int it = 0; it < 8; ++it) {
            int4 mv = Ms[it * 64 + lane];
            unsigned long long b0 = __ballot(mv.x != 0);
            unsigned long long b1 = __ballot(mv.y != 0);
            unsigned long long b2 = __ballot(mv.z != 0);
            unsigned long long b3 = __ballot(mv.w != 0);
            if (lane == 0) {
                unsigned long long* dst = &fM[row * 33 + it * 4];
                dst[0] = b0; dst[1] = b1; dst[2] = b2; dst[3] = b3;
            }
        }
    }
    __syncthreads();

    const int qrow = w * 16 + l15;
    bf16x8 qa0 = *(const bf16x8*)&fQ[qrow * 72 + quad * 8];
    bf16x8 qa1 = *(const bf16x8*)&fQ[qrow * 72 + quad * 8 + 32];

    float lsum[4] = {0.f, 0.f, 0.f, 0.f};
    for (int kt = 0; kt < 32; ++kt) {
        const int k0 = kt * 64;
        __syncthreads();
        {
            const float2* Ks = (const float2*)(Kb + (size_t)k0 * D);
            for (int i = 0; i < 8; ++i) {
                int idx = i * 256 + tid;
                int row = idx >> 5, d2 = idx & 31;
                float2 val = Ks[idx];
                unsigned pk = f2bf(val.x) | (f2bf(val.y) << 16);
                *(unsigned*)&fK[row * 72 + d2 * 2] = pk;
            }
        }
        __syncthreads();
        f32x4 acc[4];
        for (int nt = 0; nt < 4; ++nt) {
            bf16x8 b0 = *(const bf16x8*)&fK[(nt * 16 + l15) * 72 + quad * 8];
            bf16x8 b1 = *(const bf16x8*)&fK[(nt * 16 + l15) * 72 + quad * 8 + 32];
            f32x4 c = {0.f, 0.f, 0.f, 0.f};
            c = __builtin_amdgcn_mfma_f32_16x16x32_bf16(qa0, b0, c, 0, 0, 0);
            c = __builtin_amdgcn_mfma_f32_16x16x32_bf16(qa1, b1, c, 0, 0, 0);
            acc[nt] = c;
        }
        const int widx = (k0 >> 8) * 4 + (lane & 3);
        const int bsh0 = (k0 >> 2) + (l15 >> 2);
        for (int r = 0; r < 4; ++r) {
            int row = w * 16 + quad * 4 + r;
            unsigned long long mwv = fM[row * 33 + widx];
            float s = 0.f;
            for (int nt = 0; nt < 4; ++nt) {
                float val = acc[nt][r] * SCALE;
                int bit = (int)((mwv >> ((bsh0 + nt * 4) & 63)) & 1ull);
                val = bit ? MASK_FILL : val;
                s += __expf(val);
            }
            lsum[r] += s;
        }
    }
    for (int off = 1; off < 16; off <<= 1)
        for (int r = 0; r < 4; ++r) lsum[r] += __shfl_xor(lsum[r], off, 64);
    float rinv[4];
    for (int r = 0; r < 4; ++r) rinv[r] = 1.0f / lsum[r];

    f32x4 oacc[4];
    for (int nt = 0; nt < 4; ++nt) oacc[nt] = (f32x4){0.f, 0.f, 0.f, 0.f};

    for (int kt = 0; kt < 32; ++kt) {
        const int k0 = kt * 64;
        __syncthreads();
        {
            const float2* Ks = (const float2*)(Kb + (size_t)k0 * D);
            for (int i = 0; i < 8; ++i) {
                int idx = i * 256 + tid;
                int row = idx >> 5, d2 = idx & 31;
                float2 val = Ks[idx];
                unsigned pk = f2bf(val.x) | (f2bf(val.y) << 16);
                *(unsigned*)&fK[row * 72 + d2 * 2] = pk;
            }
        }
        {
            unsigned pk[8];
            for (int jj = 0; jj < 16; ++jj) {
                float val = Vb[(size_t)(k0 + w * 16 + jj) * D + lane];
                unsigned bv = f2bf(val);
                if (jj & 1) pk[jj >> 1] |= bv << 16;
                else        pk[jj >> 1]  = bv;
            }
            uint4* dst = (uint4*)&fVt[lane * 72 + w * 16];
            dst[0] = make_uint4(pk[0], pk[1], pk[2], pk[3]);
            dst[1] = make_uint4(pk[4], pk[5], pk[6], pk[7]);
        }
        __syncthreads();
        f32x4 acc[4];
        for (int nt = 0; nt < 4; ++nt) {
            bf16x8 b0 = *(const bf16x8*)&fK[(nt * 16 + l15) * 72 + quad * 8];
            bf16x8 b1 = *(const bf16x8*)&fK[(nt * 16 + l15) * 72 + quad * 8 + 32];
            f32x4 c = {0.f, 0.f, 0.f, 0.f};
            c = __builtin_amdgcn_mfma_f32_16x16x32_bf16(qa0, b0, c, 0, 0, 0);
            c = __builtin_amdgcn_mfma_f32_16x16x32_bf16(qa1, b1, c, 0, 0, 0);
            acc[nt] = c;
        }
        const int widx = (k0 >> 8) * 4 + (lane & 3);
        const int bsh0 = (k0 >> 2) + (l15 >> 2);
        for (int r = 0; r < 4; ++r) {
            int row = w * 16 + quad * 4 + r;
            unsigned long long mwv = fM[row * 33 + widx];
            for (int nt = 0; nt < 4; ++nt) {
                float val = acc[nt][r] * SCALE;
                int bit = (int)((mwv >> ((bsh0 + nt * 4) & 63)) & 1ull);
                val = bit ? MASK_FILL : val;
                float pr = __expf(val) * rinv[r];
                fP[row * 72 + nt * 16 + l15] = (unsigned short)f2bf(pr);
            }
        }
        for (int it = 0; it < 4; ++it) {
            int row = w * 16 + it * 4 + quad;
            unsigned long long pv = *(const unsigned long long*)&fP[row * 72 + l15 * 4];
            float4 o;
            o.x = bf2f((unsigned short)(pv         & 0xFFFF));
            o.y = bf2f((unsigned short)((pv >> 16) & 0xFFFF));
            o.z = bf2f((unsigned short)((pv >> 32) & 0xFFFF));
            o.w = bf2f((unsigned short)((pv >> 48) & 0xFFFF));
            *(float4*)&Ab[(size_t)row * L + k0 + l15 * 4] = o;
        }
        {
            bf16x8 pa0 = *(const bf16x8*)&fP[qrow * 72 + quad * 8];
            bf16x8 pa1 = *(const bf16x8*)&fP[qrow * 72 + quad * 8 + 32];
            for (int nt = 0; nt < 4; ++nt) {
                bf16x8 vb0 = *(const bf16x8*)&fVt[(nt * 16 + l15) * 72 + quad * 8];
                bf16x8 vb1 = *(const bf16x8*)&fVt[(nt * 16 + l15) * 72 + quad * 8 + 32];
                oacc[nt] = __builtin_amdgcn_mfma_f32_16x16x32_bf16(pa0, vb0, oacc[nt], 0, 0, 0);
                oacc[nt] = __builtin_amdgcn_mfma_f32_16x16x32_bf16(pa1, vb1, oacc[nt], 0, 0, 0);
            }
        }
    }
    for (int nt = 0; nt < 4; ++nt)
        for (int r = 0; r < 4; ++r)
            Ob[(size_t)(w * 16 + quad * 4 + r) * D + nt * 16 + l15] = oacc[nt][r];
}

// ============================== launch ====================================

extern "C" void kernel_launch(void* const* d_in, const int* in_sizes, int n_in,
                              void* d_out, int out_size, void* d_ws, size_t ws_size,
                              hipStream_t stream)
{
    const float* q    = (const float*)d_in[0];
    const float* k    = (const float*)d_in[1];
    const float* v    = (const float*)d_in[2];
    const int*   mask = (const int*)d_in[3];
    float* out  = (float*)d_out;
    float* attn = out + (size_t)BH * L * D;

    const size_t WS_K  = 0;
    const size_t WS_VT = (size_t)BH * L * D * 2;            // 4 MB
    const size_t WS_M  = WS_VT + (size_t)BH * L * D * 2;    // 8 MB
    const size_t NEED  = WS_M + (size_t)BH * L * 64 * 4;    // 16 MB

    if (ws_size >= NEED) {
        uint4* wsK  = (uint4*)((char*)d_ws + WS_K);
        uint4* wsVt = (uint4*)((char*)d_ws + WS_VT);
        unsigned* wsM2 = (unsigned*)((char*)d_ws + WS_M);
        hipLaunchKernelGGL(prep, dim3(3584), dim3(256), 0, stream,
                           k, v, mask, wsK, wsVt, wsM2);
        hipLaunchKernelGGL(sdpa_main, dim3(BH * (L / QB)), dim3(256), 0, stream,
                           q, (const uint4*)wsK, (const uint4*)wsVt, wsM2, out, attn);
    } else {
        hipLaunchKernelGGL(sdpa_kernel, dim3(BH * (L / 64)), dim3(256), 0, stream,
                           q, k, v, mask, out, attn);
    }
}